// Round 1
// baseline (942.056 us; speedup 1.0000x reference)
//
#include <hip/hip_runtime.h>
#include <math.h>

// Problem constants (from reference)
constexpr int B_ = 16, T_ = 256, D_ = 384, M_ = 2048, F_ = 256, NMEL_ = 80;
constexpr float PACE_ = 1.0f, MAXDUR_ = 75.0f;

// ---------------------------------------------------------------------------
// Fused Conv1d(K=3, SAME) + ReLU + LayerNorm(over channels)
// x: [B,T,CIN] (optionally * mask[B,T]), w: [F_,CIN,3], y: [B,T,F_]
// Block: 256 threads = 1 per output filter; tile of TT=16 timesteps.
// ---------------------------------------------------------------------------
template <int CIN>
__global__ __launch_bounds__(256) void conv_relu_ln(
    const float* __restrict__ x, const float* __restrict__ mask,
    const float* __restrict__ w, const float* __restrict__ bias,
    const float* __restrict__ gam, const float* __restrict__ bet,
    float* __restrict__ y)
{
    constexpr int TT = 16;
    __shared__ float xs[(TT + 2) * CIN];
    __shared__ float hs[TT][F_ + 1];   // +1 pad: conflict-free strided stats reads
    __shared__ float mu_s[TT], rs_s[TT];

    const int b  = blockIdx.y;
    const int t0 = blockIdx.x * TT;
    const int f  = threadIdx.x;

    // Stage x rows t0-1 .. t0+TT (zero-padded) into LDS, coalesced.
    for (int i = f; i < (TT + 2) * CIN; i += 256) {
        const int j = i / CIN, d = i - j * CIN;
        const int t = t0 - 1 + j;
        float v = 0.f;
        if (t >= 0 && t < T_) {
            v = x[((size_t)b * T_ + t) * CIN + d];
            if (mask) v *= mask[b * T_ + t];
        }
        xs[i] = v;
    }
    __syncthreads();

    float acc[TT];
    {
        const float bb = bias[f];
#pragma unroll
        for (int t = 0; t < TT; t++) acc[t] = bb;
    }

    // Per-thread weight row is contiguous: w[f, :, :] = CIN*3 floats.
    const float* wf = w + (size_t)f * CIN * 3;
    for (int d = 0; d < CIN; d += 4) {
        const float4 w0 = *(const float4*)(wf + d * 3);
        const float4 w1 = *(const float4*)(wf + d * 3 + 4);
        const float4 w2 = *(const float4*)(wf + d * 3 + 8);
        float4 xv[TT + 2];
#pragma unroll
        for (int j = 0; j < TT + 2; j++)
            xv[j] = *(const float4*)(&xs[j * CIN + d]);  // broadcast ds_read_b128
#pragma unroll
        for (int t = 0; t < TT; t++) {
            float a = acc[t];
            // channel d+0 (taps k=0..2), weight layout w[f][d][k]
            a = fmaf(w0.x, xv[t].x,     a);
            a = fmaf(w0.y, xv[t + 1].x, a);
            a = fmaf(w0.z, xv[t + 2].x, a);
            // channel d+1
            a = fmaf(w0.w, xv[t].y,     a);
            a = fmaf(w1.x, xv[t + 1].y, a);
            a = fmaf(w1.y, xv[t + 2].y, a);
            // channel d+2
            a = fmaf(w1.z, xv[t].z,     a);
            a = fmaf(w1.w, xv[t + 1].z, a);
            a = fmaf(w2.x, xv[t + 2].z, a);
            // channel d+3
            a = fmaf(w2.y, xv[t].w,     a);
            a = fmaf(w2.z, xv[t + 1].w, a);
            a = fmaf(w2.w, xv[t + 2].w, a);
            acc[t] = a;
        }
    }

#pragma unroll
    for (int t = 0; t < TT; t++) hs[t][f] = fmaxf(acc[t], 0.f);
    __syncthreads();

    // LayerNorm stats: 16 threads per timestep (TT=16 * 16 = 256).
    {
        const int tt = f >> 4, s = f & 15;
        float sm = 0.f, sq = 0.f;
#pragma unroll
        for (int i = 0; i < 16; i++) {
            const float v = hs[tt][s + 16 * i];
            sm += v; sq += v * v;
        }
#pragma unroll
        for (int off = 8; off >= 1; off >>= 1) {
            sm += __shfl_xor(sm, off);
            sq += __shfl_xor(sq, off);
        }
        if (s == 0) {
            const float m   = sm * (1.f / F_);
            const float var = sq * (1.f / F_) - m * m;
            mu_s[tt] = m;
            rs_s[tt] = rsqrtf(var + 1e-5f);
        }
    }
    __syncthreads();

    const float gg = gam[f], bb2 = bet[f];
#pragma unroll
    for (int t = 0; t < TT; t++) {
        const float v = (hs[t][f] - mu_s[t]) * rs_s[t] * gg + bb2;
        y[((size_t)b * T_ + t0 + t) * F_ + f] = v;
    }
}

// ---------------------------------------------------------------------------
// FC head: pred[row] = (dot(h[row,:256], fcw) + fcb) * mask[row]
// One 64-lane wave per row; optional fused dur_pred = clip(exp(p)-1, 0, 75).
// ---------------------------------------------------------------------------
__global__ __launch_bounds__(256) void fc_mask_kernel(
    const float* __restrict__ h, const float* __restrict__ fcw,
    const float* __restrict__ fcb, const float* __restrict__ mask,
    float* __restrict__ pred, float* __restrict__ durpred)
{
    const int row  = blockIdx.x * 4 + (threadIdx.x >> 6);
    const int lane = threadIdx.x & 63;
    const float4 hv = *(const float4*)(h + (size_t)row * F_ + lane * 4);
    const float4 wv = *(const float4*)(fcw + lane * 4);
    float s = hv.x * wv.x + hv.y * wv.y + hv.z * wv.z + hv.w * wv.w;
#pragma unroll
    for (int off = 32; off >= 1; off >>= 1) s += __shfl_xor(s, off);
    if (lane == 0) {
        const float p = (s + fcb[0]) * mask[row];
        pred[row] = p;
        if (durpred) durpred[row] = fminf(fmaxf(expf(p) - 1.f, 0.f), MAXDUR_);
    }
}

// ---------------------------------------------------------------------------
// enc[b,t,d] = enc_out[b,t,d] + Conv1d(1->D,K=3)(pitch_tgt)[b,d,t]
// ---------------------------------------------------------------------------
__global__ __launch_bounds__(256) void pitch_add_kernel(
    const float* __restrict__ enc_out, const float* __restrict__ pt,
    const float* __restrict__ we, const float* __restrict__ be,
    float* __restrict__ enc)
{
    const int gid = blockIdx.x * 256 + threadIdx.x;  // over B*T*D exactly
    const int d  = gid % D_;
    const int bt = gid / D_;
    const int t = bt % T_, b = bt / T_;
    float s = be[d];
#pragma unroll
    for (int k = 0; k < 3; k++) {
        const int t2 = t - 1 + k;
        if (t2 >= 0 && t2 < T_) s = fmaf(we[d * 3 + k], pt[b * T_ + t2], s);
    }
    enc[gid] = enc_out[gid] + s;
}

// ---------------------------------------------------------------------------
// regulate_len prep: per-batch cumsum of reps, then searchsorted-right per
// output frame -> phoneme index, plus dec_mask. One block per batch sample.
// ---------------------------------------------------------------------------
__global__ __launch_bounds__(256) void regulate_kernel(
    const int* __restrict__ dur, int* __restrict__ idx_out,
    float* __restrict__ dec_mask)
{
    __shared__ int cums[T_];
    const int b = blockIdx.x, t = threadIdx.x;
    cums[t] = (int)rintf((float)dur[b * T_ + t] / PACE_);
    __syncthreads();
    for (int off = 1; off < T_; off <<= 1) {
        int v = cums[t];
        if (t >= off) v += cums[t - off];
        __syncthreads();
        cums[t] = v;
        __syncthreads();
    }
    const int dec_len = min(cums[T_ - 1], M_);
#pragma unroll
    for (int r = 0; r < M_ / T_; r++) {
        const int j = r * T_ + t;
        int lo = 0, hi = T_;            // upper_bound: first i with cums[i] > j
        while (lo < hi) {
            const int mid = (lo + hi) >> 1;
            if (cums[mid] <= j) lo = mid + 1; else hi = mid;
        }
        idx_out[b * M_ + j]  = min(lo, T_ - 1);
        dec_mask[b * M_ + j] = (j < dec_len) ? 1.f : 0.f;
    }
}

// ---------------------------------------------------------------------------
// mel[b,j,n] = mask[b,j] * dot(enc[b, idx[b,j], :], proj_w[n,:]) + proj_b[n]
// One thread per output element.
// ---------------------------------------------------------------------------
__global__ __launch_bounds__(256) void mel_kernel(
    const float* __restrict__ enc, const int* __restrict__ idx,
    const float* __restrict__ dec_mask, const float* __restrict__ pw,
    const float* __restrict__ pb, float* __restrict__ mel)
{
    const int gid = blockIdx.x * 256 + threadIdx.x;  // B*M*NMEL = 10240*256
    const int n  = gid % NMEL_;
    const int bj = gid / NMEL_;
    const int b  = bj / M_;
    const int id = idx[bj];
    const float m = dec_mask[bj];
    const float* er = enc + ((size_t)b * T_ + id) * D_;
    const float* wr = pw + (size_t)n * D_;
    float s = 0.f;
#pragma unroll 4
    for (int i = 0; i < D_; i += 4) {
        const float4 e = *(const float4*)(er + i);
        const float4 v = *(const float4*)(wr + i);
        s = fmaf(e.x, v.x, s); s = fmaf(e.y, v.y, s);
        s = fmaf(e.z, v.z, s); s = fmaf(e.w, v.w, s);
    }
    mel[gid] = m * s + pb[n];
}

// ---------------------------------------------------------------------------
extern "C" void kernel_launch(void* const* d_in, const int* in_sizes, int n_in,
                              void* d_out, int out_size, void* d_ws, size_t ws_size,
                              hipStream_t stream)
{
    const float* enc_out   = (const float*)d_in[0];
    const float* enc_mask  = (const float*)d_in[1];
    const float* pitch_tgt = (const float*)d_in[2];
    const int*   durations = (const int*)d_in[3];

    const float* dur_c0_w = (const float*)d_in[4];
    const float* dur_c0_b = (const float*)d_in[5];
    const float* dur_n0_g = (const float*)d_in[6];
    const float* dur_n0_b = (const float*)d_in[7];
    const float* dur_c1_w = (const float*)d_in[8];
    const float* dur_c1_b = (const float*)d_in[9];
    const float* dur_n1_g = (const float*)d_in[10];
    const float* dur_n1_b = (const float*)d_in[11];
    const float* dur_fc_w = (const float*)d_in[12];
    const float* dur_fc_b = (const float*)d_in[13];

    const float* pit_c0_w = (const float*)d_in[14];
    const float* pit_c0_b = (const float*)d_in[15];
    const float* pit_n0_g = (const float*)d_in[16];
    const float* pit_n0_b = (const float*)d_in[17];
    const float* pit_c1_w = (const float*)d_in[18];
    const float* pit_c1_b = (const float*)d_in[19];
    const float* pit_n1_g = (const float*)d_in[20];
    const float* pit_n1_b = (const float*)d_in[21];
    const float* pit_fc_w = (const float*)d_in[22];
    const float* pit_fc_b = (const float*)d_in[23];

    const float* pemb_w = (const float*)d_in[24];
    const float* pemb_b = (const float*)d_in[25];
    const float* proj_w = (const float*)d_in[26];
    const float* proj_b = (const float*)d_in[27];

    // Output slices (flat, in return order), all fp32.
    float* out       = (float*)d_out;
    float* mel_out   = out;                                   // [B,M,NMEL]
    float* dec_mask  = mel_out + (size_t)B_ * M_ * NMEL_;     // [B,M,1]
    float* dur_pred  = dec_mask + (size_t)B_ * M_;            // [B,T]
    float* log_dur   = dur_pred + (size_t)B_ * T_;            // [B,T]
    float* pitch_prd = log_dur + (size_t)B_ * T_;             // [B,T]

    // Workspace layout (~14.5 MB)
    float* hA  = (float*)d_ws;                     // [B,T,256]
    float* hB  = hA + (size_t)B_ * T_ * F_;        // [B,T,256]
    float* enc = hB + (size_t)B_ * T_ * F_;        // [B,T,D]
    int*   idx = (int*)(enc + (size_t)B_ * T_ * D_);  // [B,M]

    const dim3 blk(256);
    const dim3 gconv(T_ / 16, B_);

    // Duration predictor
    conv_relu_ln<D_><<<gconv, blk, 0, stream>>>(enc_out, enc_mask, dur_c0_w, dur_c0_b, dur_n0_g, dur_n0_b, hA);
    conv_relu_ln<F_><<<gconv, blk, 0, stream>>>(hA, nullptr, dur_c1_w, dur_c1_b, dur_n1_g, dur_n1_b, hB);
    fc_mask_kernel<<<B_ * T_ / 4, blk, 0, stream>>>(hB, dur_fc_w, dur_fc_b, enc_mask, log_dur, dur_pred);

    // Pitch predictor
    conv_relu_ln<D_><<<gconv, blk, 0, stream>>>(enc_out, enc_mask, pit_c0_w, pit_c0_b, pit_n0_g, pit_n0_b, hA);
    conv_relu_ln<F_><<<gconv, blk, 0, stream>>>(hA, nullptr, pit_c1_w, pit_c1_b, pit_n1_g, pit_n1_b, hB);
    fc_mask_kernel<<<B_ * T_ / 4, blk, 0, stream>>>(hB, pit_fc_w, pit_fc_b, enc_mask, pitch_prd, nullptr);

    // Pitch embedding conv + residual add
    pitch_add_kernel<<<B_ * T_ * D_ / 256, blk, 0, stream>>>(enc_out, pitch_tgt, pemb_w, pemb_b, enc);

    // Length regulation indices + mask
    regulate_kernel<<<B_, blk, 0, stream>>>(durations, idx, dec_mask);

    // Gather + projection to mel
    mel_kernel<<<B_ * M_ * NMEL_ / 256, blk, 0, stream>>>(enc, idx, dec_mask, proj_w, proj_b, mel_out);
}

// Round 2
// 473.660 us; speedup vs baseline: 1.9889x; 1.9889x over previous
//
#include <hip/hip_runtime.h>
#include <math.h>

// Problem constants (from reference)
constexpr int B_ = 16, T_ = 256, D_ = 384, M_ = 2048, F_ = 256, NMEL_ = 80;
constexpr float PACE_ = 1.0f, MAXDUR_ = 75.0f;

// ---------------------------------------------------------------------------
// Fused Conv1d(K=3, SAME) + ReLU + LayerNorm(over channels)
// x: [B,T,CIN] (optionally * mask[B,T]), w: [F_,CIN,3], y: [B,T,F_]
// Block: 256 threads = 1 per output filter; tile of TT=16 timesteps.
// ---------------------------------------------------------------------------
template <int CIN>
__global__ __launch_bounds__(256) void conv_relu_ln(
    const float* __restrict__ x, const float* __restrict__ mask,
    const float* __restrict__ w, const float* __restrict__ bias,
    const float* __restrict__ gam, const float* __restrict__ bet,
    float* __restrict__ y)
{
    constexpr int TT = 16;
    __shared__ float xs[(TT + 2) * CIN];
    __shared__ float hs[TT][F_ + 1];   // +1 pad: conflict-free strided stats reads
    __shared__ float mu_s[TT], rs_s[TT];

    const int b  = blockIdx.y;
    const int t0 = blockIdx.x * TT;
    const int f  = threadIdx.x;

    // Stage x rows t0-1 .. t0+TT (zero-padded) into LDS, coalesced.
    for (int i = f; i < (TT + 2) * CIN; i += 256) {
        const int j = i / CIN, d = i - j * CIN;
        const int t = t0 - 1 + j;
        float v = 0.f;
        if (t >= 0 && t < T_) {
            v = x[((size_t)b * T_ + t) * CIN + d];
            if (mask) v *= mask[b * T_ + t];
        }
        xs[i] = v;
    }
    __syncthreads();

    float acc[TT];
    {
        const float bb = bias[f];
#pragma unroll
        for (int t = 0; t < TT; t++) acc[t] = bb;
    }

    // Per-thread weight row is contiguous: w[f, :, :] = CIN*3 floats.
    const float* wf = w + (size_t)f * CIN * 3;
    for (int d = 0; d < CIN; d += 4) {
        const float4 w0 = *(const float4*)(wf + d * 3);
        const float4 w1 = *(const float4*)(wf + d * 3 + 4);
        const float4 w2 = *(const float4*)(wf + d * 3 + 8);
        float4 xv[TT + 2];
#pragma unroll
        for (int j = 0; j < TT + 2; j++)
            xv[j] = *(const float4*)(&xs[j * CIN + d]);  // broadcast ds_read_b128
#pragma unroll
        for (int t = 0; t < TT; t++) {
            float a = acc[t];
            a = fmaf(w0.x, xv[t].x,     a);
            a = fmaf(w0.y, xv[t + 1].x, a);
            a = fmaf(w0.z, xv[t + 2].x, a);
            a = fmaf(w0.w, xv[t].y,     a);
            a = fmaf(w1.x, xv[t + 1].y, a);
            a = fmaf(w1.y, xv[t + 2].y, a);
            a = fmaf(w1.z, xv[t].z,     a);
            a = fmaf(w1.w, xv[t + 1].z, a);
            a = fmaf(w2.x, xv[t + 2].z, a);
            a = fmaf(w2.y, xv[t].w,     a);
            a = fmaf(w2.z, xv[t + 1].w, a);
            a = fmaf(w2.w, xv[t + 2].w, a);
            acc[t] = a;
        }
    }

#pragma unroll
    for (int t = 0; t < TT; t++) hs[t][f] = fmaxf(acc[t], 0.f);
    __syncthreads();

    // LayerNorm stats: 16 threads per timestep (TT=16 * 16 = 256).
    {
        const int tt = f >> 4, s = f & 15;
        float sm = 0.f, sq = 0.f;
#pragma unroll
        for (int i = 0; i < 16; i++) {
            const float v = hs[tt][s + 16 * i];
            sm += v; sq += v * v;
        }
#pragma unroll
        for (int off = 8; off >= 1; off >>= 1) {
            sm += __shfl_xor(sm, off);
            sq += __shfl_xor(sq, off);
        }
        if (s == 0) {
            const float m   = sm * (1.f / F_);
            const float var = sq * (1.f / F_) - m * m;
            mu_s[tt] = m;
            rs_s[tt] = rsqrtf(var + 1e-5f);
        }
    }
    __syncthreads();

    const float gg = gam[f], bb2 = bet[f];
#pragma unroll
    for (int t = 0; t < TT; t++) {
        const float v = (hs[t][f] - mu_s[t]) * rs_s[t] * gg + bb2;
        y[((size_t)b * T_ + t0 + t) * F_ + f] = v;
    }
}

// ---------------------------------------------------------------------------
// FC head: pred[row] = (dot(h[row,:256], fcw) + fcb) * mask[row]
// One 64-lane wave per row; optional fused dur_pred = clip(exp(p)-1, 0, 75).
// ---------------------------------------------------------------------------
__global__ __launch_bounds__(256) void fc_mask_kernel(
    const float* __restrict__ h, const float* __restrict__ fcw,
    const float* __restrict__ fcb, const float* __restrict__ mask,
    float* __restrict__ pred, float* __restrict__ durpred)
{
    const int row  = blockIdx.x * 4 + (threadIdx.x >> 6);
    const int lane = threadIdx.x & 63;
    const float4 hv = *(const float4*)(h + (size_t)row * F_ + lane * 4);
    const float4 wv = *(const float4*)(fcw + lane * 4);
    float s = hv.x * wv.x + hv.y * wv.y + hv.z * wv.z + hv.w * wv.w;
#pragma unroll
    for (int off = 32; off >= 1; off >>= 1) s += __shfl_xor(s, off);
    if (lane == 0) {
        const float p = (s + fcb[0]) * mask[row];
        pred[row] = p;
        if (durpred) durpred[row] = fminf(fmaxf(expf(p) - 1.f, 0.f), MAXDUR_);
    }
}

// ---------------------------------------------------------------------------
// enc[b,t,d] = enc_out[b,t,d] + Conv1d(1->D,K=3)(pitch_tgt)[b,d,t]
// ---------------------------------------------------------------------------
__global__ __launch_bounds__(256) void pitch_add_kernel(
    const float* __restrict__ enc_out, const float* __restrict__ pt,
    const float* __restrict__ we, const float* __restrict__ be,
    float* __restrict__ enc)
{
    const int gid = blockIdx.x * 256 + threadIdx.x;  // over B*T*D exactly
    const int d  = gid % D_;
    const int bt = gid / D_;
    const int t = bt % T_, b = bt / T_;
    float s = be[d];
#pragma unroll
    for (int k = 0; k < 3; k++) {
        const int t2 = t - 1 + k;
        if (t2 >= 0 && t2 < T_) s = fmaf(we[d * 3 + k], pt[b * T_ + t2], s);
    }
    enc[gid] = enc_out[gid] + s;
}

// ---------------------------------------------------------------------------
// regulate_len prep: per-batch cumsum of reps, then searchsorted-right per
// output frame -> phoneme index, plus dec_mask. One block per batch sample.
// ---------------------------------------------------------------------------
__global__ __launch_bounds__(256) void regulate_kernel(
    const int* __restrict__ dur, int* __restrict__ idx_out,
    float* __restrict__ dec_mask)
{
    __shared__ int cums[T_];
    const int b = blockIdx.x, t = threadIdx.x;
    cums[t] = (int)rintf((float)dur[b * T_ + t] / PACE_);
    __syncthreads();
    for (int off = 1; off < T_; off <<= 1) {
        int v = cums[t];
        if (t >= off) v += cums[t - off];
        __syncthreads();
        cums[t] = v;
        __syncthreads();
    }
    const int dec_len = min(cums[T_ - 1], M_);
#pragma unroll
    for (int r = 0; r < M_ / T_; r++) {
        const int j = r * T_ + t;
        int lo = 0, hi = T_;            // upper_bound: first i with cums[i] > j
        while (lo < hi) {
            const int mid = (lo + hi) >> 1;
            if (cums[mid] <= j) lo = mid + 1; else hi = mid;
        }
        idx_out[b * M_ + j]  = min(lo, T_ - 1);
        dec_mask[b * M_ + j] = (j < dec_len) ? 1.f : 0.f;
    }
}

// ---------------------------------------------------------------------------
// mel tiled gather-GEMM:
//   mel[b,j,n] = dec_mask[b,j] * dot(enc[b, idx[b,j], :], proj_w[n,:]) + proj_b[n]
// Block = (b, tile of JT=32 j). A-tile (gathered enc rows) and proj_w K-chunks
// staged in LDS with coalesced float4 loads; thread register-blocks 2j x 5n.
// Row pad +4 floats => strided LDS reads are only 2-way aliased (free).
// ---------------------------------------------------------------------------
constexpr int JT_ = 32;     // j rows per block
constexpr int DK_ = 128;    // K-chunk
constexpr int LDP_ = DK_ + 4;  // padded row stride (528 B, float4-aligned)

__global__ __launch_bounds__(256) void mel_tiled_kernel(
    const float* __restrict__ enc, const int* __restrict__ idx,
    const float* __restrict__ dec_mask, const float* __restrict__ pw,
    const float* __restrict__ pb, float* __restrict__ mel)
{
    __shared__ float As[JT_][LDP_];    // 32 x 132 x 4B = 16.9 KB
    __shared__ float Ws[NMEL_][LDP_];  // 80 x 132 x 4B = 42.2 KB
    __shared__ int   ids[JT_];

    const int b   = blockIdx.y;
    const int j0  = blockIdx.x * JT_;
    const int tid = threadIdx.x;

    if (tid < JT_) ids[tid] = idx[b * M_ + j0 + tid];
    __syncthreads();

    const int tx = tid & 15;   // n-group: n = tx*5 .. tx*5+4
    const int ty = tid >> 4;   // j-group: j = ty*2 .. ty*2+1
    const int nb = tx * 5;
    const int jb = ty * 2;

    float acc[2][5];
#pragma unroll
    for (int jj = 0; jj < 2; jj++)
#pragma unroll
        for (int k = 0; k < 5; k++) acc[jj][k] = 0.f;

    for (int d0 = 0; d0 < D_; d0 += DK_) {
        // Stage A-tile chunk: 32 rows x 128 floats (coalesced float4)
        for (int i = tid; i < JT_ * (DK_ / 4); i += 256) {
            const int jj = i / (DK_ / 4);
            const int dd = (i - jj * (DK_ / 4)) * 4;
            const float4 v = *(const float4*)(
                enc + ((size_t)b * T_ + ids[jj]) * D_ + d0 + dd);
            *(float4*)(&As[jj][dd]) = v;
        }
        // Stage W chunk: 80 rows x 128 floats (coalesced float4)
        for (int i = tid; i < NMEL_ * (DK_ / 4); i += 256) {
            const int nn = i / (DK_ / 4);
            const int dd = (i - nn * (DK_ / 4)) * 4;
            *(float4*)(&Ws[nn][dd]) =
                *(const float4*)(pw + (size_t)nn * D_ + d0 + dd);
        }
        __syncthreads();

#pragma unroll 4
        for (int d = 0; d < DK_; d += 4) {
            const float4 a0 = *(const float4*)(&As[jb + 0][d]);
            const float4 a1 = *(const float4*)(&As[jb + 1][d]);
#pragma unroll
            for (int k = 0; k < 5; k++) {
                const float4 wv = *(const float4*)(&Ws[nb + k][d]);
                float s0 = acc[0][k], s1 = acc[1][k];
                s0 = fmaf(a0.x, wv.x, s0); s1 = fmaf(a1.x, wv.x, s1);
                s0 = fmaf(a0.y, wv.y, s0); s1 = fmaf(a1.y, wv.y, s1);
                s0 = fmaf(a0.z, wv.z, s0); s1 = fmaf(a1.z, wv.z, s1);
                s0 = fmaf(a0.w, wv.w, s0); s1 = fmaf(a1.w, wv.w, s1);
                acc[0][k] = s0; acc[1][k] = s1;
            }
        }
        __syncthreads();
    }

#pragma unroll
    for (int jj = 0; jj < 2; jj++) {
        const int bj = b * M_ + j0 + jb + jj;
        const float m = dec_mask[bj];
#pragma unroll
        for (int k = 0; k < 5; k++)
            mel[(size_t)bj * NMEL_ + nb + k] = m * acc[jj][k] + pb[nb + k];
    }
}

// ---------------------------------------------------------------------------
extern "C" void kernel_launch(void* const* d_in, const int* in_sizes, int n_in,
                              void* d_out, int out_size, void* d_ws, size_t ws_size,
                              hipStream_t stream)
{
    const float* enc_out   = (const float*)d_in[0];
    const float* enc_mask  = (const float*)d_in[1];
    const float* pitch_tgt = (const float*)d_in[2];
    const int*   durations = (const int*)d_in[3];

    const float* dur_c0_w = (const float*)d_in[4];
    const float* dur_c0_b = (const float*)d_in[5];
    const float* dur_n0_g = (const float*)d_in[6];
    const float* dur_n0_b = (const float*)d_in[7];
    const float* dur_c1_w = (const float*)d_in[8];
    const float* dur_c1_b = (const float*)d_in[9];
    const float* dur_n1_g = (const float*)d_in[10];
    const float* dur_n1_b = (const float*)d_in[11];
    const float* dur_fc_w = (const float*)d_in[12];
    const float* dur_fc_b = (const float*)d_in[13];

    const float* pit_c0_w = (const float*)d_in[14];
    const float* pit_c0_b = (const float*)d_in[15];
    const float* pit_n0_g = (const float*)d_in[16];
    const float* pit_n0_b = (const float*)d_in[17];
    const float* pit_c1_w = (const float*)d_in[18];
    const float* pit_c1_b = (const float*)d_in[19];
    const float* pit_n1_g = (const float*)d_in[20];
    const float* pit_n1_b = (const float*)d_in[21];
    const float* pit_fc_w = (const float*)d_in[22];
    const float* pit_fc_b = (const float*)d_in[23];

    const float* pemb_w = (const float*)d_in[24];
    const float* pemb_b = (const float*)d_in[25];
    const float* proj_w = (const float*)d_in[26];
    const float* proj_b = (const float*)d_in[27];

    // Output slices (flat, in return order), all fp32.
    float* out       = (float*)d_out;
    float* mel_out   = out;                                   // [B,M,NMEL]
    float* dec_mask  = mel_out + (size_t)B_ * M_ * NMEL_;     // [B,M,1]
    float* dur_pred  = dec_mask + (size_t)B_ * M_;            // [B,T]
    float* log_dur   = dur_pred + (size_t)B_ * T_;            // [B,T]
    float* pitch_prd = log_dur + (size_t)B_ * T_;             // [B,T]

    // Workspace layout (~14.5 MB)
    float* hA  = (float*)d_ws;                     // [B,T,256]
    float* hB  = hA + (size_t)B_ * T_ * F_;        // [B,T,256]
    float* enc = hB + (size_t)B_ * T_ * F_;        // [B,T,D]
    int*   idx = (int*)(enc + (size_t)B_ * T_ * D_);  // [B,M]

    const dim3 blk(256);
    const dim3 gconv(T_ / 16, B_);

    // Duration predictor
    conv_relu_ln<D_><<<gconv, blk, 0, stream>>>(enc_out, enc_mask, dur_c0_w, dur_c0_b, dur_n0_g, dur_n0_b, hA);
    conv_relu_ln<F_><<<gconv, blk, 0, stream>>>(hA, nullptr, dur_c1_w, dur_c1_b, dur_n1_g, dur_n1_b, hB);
    fc_mask_kernel<<<B_ * T_ / 4, blk, 0, stream>>>(hB, dur_fc_w, dur_fc_b, enc_mask, log_dur, dur_pred);

    // Pitch predictor
    conv_relu_ln<D_><<<gconv, blk, 0, stream>>>(enc_out, enc_mask, pit_c0_w, pit_c0_b, pit_n0_g, pit_n0_b, hA);
    conv_relu_ln<F_><<<gconv, blk, 0, stream>>>(hA, nullptr, pit_c1_w, pit_c1_b, pit_n1_g, pit_n1_b, hB);
    fc_mask_kernel<<<B_ * T_ / 4, blk, 0, stream>>>(hB, pit_fc_w, pit_fc_b, enc_mask, pitch_prd, nullptr);

    // Pitch embedding conv + residual add
    pitch_add_kernel<<<B_ * T_ * D_ / 256, blk, 0, stream>>>(enc_out, pitch_tgt, pemb_w, pemb_b, enc);

    // Length regulation indices + mask
    regulate_kernel<<<B_, blk, 0, stream>>>(durations, idx, dec_mask);

    // Gather + projection to mel
    mel_tiled_kernel<<<dim3(M_ / JT_, B_), blk, 0, stream>>>(enc, idx, dec_mask, proj_w, proj_b, mel_out);
}

// Round 3
// 299.919 us; speedup vs baseline: 3.1410x; 1.5793x over previous
//
#include <hip/hip_runtime.h>
#include <math.h>

// Problem constants (from reference)
constexpr int B_ = 16, T_ = 256, D_ = 384, M_ = 2048, F_ = 256, NMEL_ = 80;
constexpr float PACE_ = 1.0f, MAXDUR_ = 75.0f;
constexpr int R_ = B_ * T_;  // 4096 total rows

typedef __attribute__((ext_vector_type(8)))  short bf16x8;
typedef __attribute__((ext_vector_type(16))) float f32x16;

static __device__ __forceinline__ unsigned short f2bf(float x) {
    union { float f; unsigned int u; } v; v.f = x;
    const unsigned int r = v.u + 0x7fffu + ((v.u >> 16) & 1u);  // RNE
    return (unsigned short)(r >> 16);
}
static __device__ __forceinline__ float bf2f(unsigned short h) {
    union { float f; unsigned int u; } v; v.u = ((unsigned int)h) << 16;
    return v.f;
}

// ---------------------------------------------------------------------------
// Cast enc_out*mask -> bf16 [R_, D_]
// ---------------------------------------------------------------------------
__global__ __launch_bounds__(256) void cast_xb_kernel(
    const float* __restrict__ x, const float* __restrict__ mask,
    unsigned short* __restrict__ xb)
{
    const int gid = blockIdx.x * 256 + threadIdx.x;   // over R_*D_/4
    const float4 v = ((const float4*)x)[gid];
    const float m = mask[gid / (D_ / 4)];
    ushort4 o;
    o.x = f2bf(v.x * m); o.y = f2bf(v.y * m);
    o.z = f2bf(v.z * m); o.w = f2bf(v.w * m);
    ((ushort4*)xb)[gid] = o;
}

// ---------------------------------------------------------------------------
// Repack conv weight w[F_,CIN,3] fp32 -> bf16 MFMA B-fragment order:
//   pwf[ ((k*8 + fn)*(CIN/16) + c)*512 + lane*8 + j ]
//     = w[f= fn*32+(lane&31)][d= c*16+(lane>>5)*8+j][k]
// so a wave's B-frag load is 64 lanes x contiguous 16B.
// ---------------------------------------------------------------------------
template <int CIN>
__global__ __launch_bounds__(256) void repack_w_kernel(
    const float* __restrict__ w, unsigned short* __restrict__ pwf)
{
    const int gid = blockIdx.x * 256 + threadIdx.x;   // over 3*F_*CIN/8
    const int lane = gid & 63;
    const int rest = gid >> 6;
    const int c  = rest % (CIN / 16);
    const int fn = (rest / (CIN / 16)) % 8;
    const int k  = rest / ((CIN / 16) * 8);
    const int f = fn * 32 + (lane & 31);
    const int d = c * 16 + (lane >> 5) * 8;
    uint4 o;
    unsigned short* op = (unsigned short*)&o;
#pragma unroll
    for (int j = 0; j < 8; j++)
        op[j] = f2bf(w[((size_t)f * CIN + d + j) * 3 + k]);
    ((uint4*)pwf)[gid] = o;
}

// ---------------------------------------------------------------------------
// Conv1d(K=3,SAME) + bias + ReLU via MFMA 32x32x16 bf16.
// Block: 32 t-rows x 256 f, 4 waves (64 f each = 2 n-tiles), 3 tap-chains.
// A (x rows, halo-padded) from LDS; B from pre-packed global (L2-resident).
// Output h bf16 [R_, F_].
// ---------------------------------------------------------------------------
template <int CIN>
__global__ __launch_bounds__(256) void conv_mfma_kernel(
    const unsigned short* __restrict__ xb, const unsigned short* __restrict__ pwf,
    const float* __restrict__ bias, unsigned short* __restrict__ hout)
{
    constexpr int LDX = CIN + 8;     // padded row stride (bf16), 16B-aligned
    constexpr int NC  = CIN / 16;    // K-chunks
    __shared__ unsigned short xs[34 * LDX];

    const int r0  = blockIdx.x * 32;     // 32-row tiles never cross a batch
    const int bb  = r0 >> 8;
    const int tl  = r0 & 255;
    const int tid = threadIdx.x;

    // Stage x rows tl-1 .. tl+32 (34 rows), zero outside batch, coalesced 16B.
    for (int i = tid; i < 34 * (CIN / 8); i += 256) {
        const int row = i / (CIN / 8);
        const int dd  = (i - row * (CIN / 8)) * 8;
        const int t   = tl - 1 + row;
        uint4 v = make_uint4(0, 0, 0, 0);
        if (t >= 0 && t < 256)
            v = *(const uint4*)(xb + ((size_t)(bb * 256 + t)) * CIN + dd);
        *(uint4*)(&xs[row * LDX + dd]) = v;
    }
    __syncthreads();

    const int wv = tid >> 6, lane = tid & 63;
    const int m = lane & 31, half = lane >> 5;
    const int fn0 = wv * 2;

    f32x16 acc[2][3];
#pragma unroll
    for (int n = 0; n < 2; n++)
#pragma unroll
        for (int k = 0; k < 3; k++)
#pragma unroll
            for (int i = 0; i < 16; i++) acc[n][k][i] = 0.f;

    for (int c = 0; c < NC; c++) {
#pragma unroll
        for (int k = 0; k < 3; k++) {
            // A[m][k16]: row tl + m + (k-1) -> xs row (m+k); 8 bf16 at half*8
            const bf16x8 a = *(const bf16x8*)(&xs[(m + k) * LDX + c * 16 + half * 8]);
            const bf16x8 b0 = *(const bf16x8*)(
                pwf + ((((size_t)k * 8 + fn0)     * NC + c) << 9) + lane * 8);
            const bf16x8 b1 = *(const bf16x8*)(
                pwf + ((((size_t)k * 8 + fn0 + 1) * NC + c) << 9) + lane * 8);
            acc[0][k] = __builtin_amdgcn_mfma_f32_32x32x16_bf16(a, b0, acc[0][k], 0, 0, 0);
            acc[1][k] = __builtin_amdgcn_mfma_f32_32x32x16_bf16(a, b1, acc[1][k], 0, 0, 0);
        }
    }

    // Epilogue: C/D layout col=lane&31, row=(reg&3)+8*(reg>>2)+4*half  [m74/m101]
#pragma unroll
    for (int n = 0; n < 2; n++) {
        const int f = (fn0 + n) * 32 + m;
        const float bs = bias[f];
#pragma unroll
        for (int reg = 0; reg < 16; reg++) {
            const int row = (reg & 3) + 8 * (reg >> 2) + 4 * half;
            const float v = acc[n][0][reg] + acc[n][1][reg] + acc[n][2][reg] + bs;
            hout[(size_t)(r0 + row) * F_ + f] = f2bf(fmaxf(v, 0.f));
        }
    }
}

// ---------------------------------------------------------------------------
// LayerNorm over 256 channels, one wave per row. bf16 in -> bf16 out.
// ---------------------------------------------------------------------------
__global__ __launch_bounds__(256) void ln_rows_kernel(
    const unsigned short* __restrict__ h, const float* __restrict__ g,
    const float* __restrict__ be, unsigned short* __restrict__ o)
{
    const int row  = blockIdx.x * 4 + (threadIdx.x >> 6);
    const int lane = threadIdx.x & 63;
    const ushort4 hv = ((const ushort4*)(h + (size_t)row * F_))[lane];
    const float v0 = bf2f(hv.x), v1 = bf2f(hv.y), v2 = bf2f(hv.z), v3 = bf2f(hv.w);
    float sm = v0 + v1 + v2 + v3;
    float sq = v0 * v0 + v1 * v1 + v2 * v2 + v3 * v3;
#pragma unroll
    for (int off = 32; off >= 1; off >>= 1) {
        sm += __shfl_xor(sm, off);
        sq += __shfl_xor(sq, off);
    }
    const float mu = sm * (1.f / F_);
    const float rs = rsqrtf(sq * (1.f / F_) - mu * mu + 1e-5f);
    const float4 gv = ((const float4*)g)[lane];
    const float4 bv = ((const float4*)be)[lane];
    ushort4 ov;
    ov.x = f2bf((v0 - mu) * rs * gv.x + bv.x);
    ov.y = f2bf((v1 - mu) * rs * gv.y + bv.y);
    ov.z = f2bf((v2 - mu) * rs * gv.z + bv.z);
    ov.w = f2bf((v3 - mu) * rs * gv.w + bv.w);
    ((ushort4*)(o + (size_t)row * F_))[lane] = ov;
}

// ---------------------------------------------------------------------------
// FC head on bf16 h: pred[row] = (dot(h[row,:],fcw)+fcb)*mask; optional dur.
// ---------------------------------------------------------------------------
__global__ __launch_bounds__(256) void fc_mask_kernel(
    const unsigned short* __restrict__ h, const float* __restrict__ fcw,
    const float* __restrict__ fcb, const float* __restrict__ mask,
    float* __restrict__ pred, float* __restrict__ durpred)
{
    const int row  = blockIdx.x * 4 + (threadIdx.x >> 6);
    const int lane = threadIdx.x & 63;
    const ushort4 hv = ((const ushort4*)(h + (size_t)row * F_))[lane];
    const float4 wv = ((const float4*)fcw)[lane];
    float s = bf2f(hv.x) * wv.x + bf2f(hv.y) * wv.y +
              bf2f(hv.z) * wv.z + bf2f(hv.w) * wv.w;
#pragma unroll
    for (int off = 32; off >= 1; off >>= 1) s += __shfl_xor(s, off);
    if (lane == 0) {
        const float p = (s + fcb[0]) * mask[row];
        pred[row] = p;
        if (durpred) durpred[row] = fminf(fmaxf(expf(p) - 1.f, 0.f), MAXDUR_);
    }
}

// ---------------------------------------------------------------------------
// enc[b,t,d] = enc_out[b,t,d] + Conv1d(1->D,K=3)(pitch_tgt)[b,d,t]
// ---------------------------------------------------------------------------
__global__ __launch_bounds__(256) void pitch_add_kernel(
    const float* __restrict__ enc_out, const float* __restrict__ pt,
    const float* __restrict__ we, const float* __restrict__ be,
    float* __restrict__ enc)
{
    const int gid = blockIdx.x * 256 + threadIdx.x;  // over B*T*D exactly
    const int d  = gid % D_;
    const int bt = gid / D_;
    const int t = bt % T_, b = bt / T_;
    float s = be[d];
#pragma unroll
    for (int k = 0; k < 3; k++) {
        const int t2 = t - 1 + k;
        if (t2 >= 0 && t2 < T_) s = fmaf(we[d * 3 + k], pt[b * T_ + t2], s);
    }
    enc[gid] = enc_out[gid] + s;
}

// ---------------------------------------------------------------------------
// regulate_len prep: cumsum + searchsorted-right -> idx, dec_mask
// ---------------------------------------------------------------------------
__global__ __launch_bounds__(256) void regulate_kernel(
    const int* __restrict__ dur, int* __restrict__ idx_out,
    float* __restrict__ dec_mask)
{
    __shared__ int cums[T_];
    const int b = blockIdx.x, t = threadIdx.x;
    cums[t] = (int)rintf((float)dur[b * T_ + t] / PACE_);
    __syncthreads();
    for (int off = 1; off < T_; off <<= 1) {
        int v = cums[t];
        if (t >= off) v += cums[t - off];
        __syncthreads();
        cums[t] = v;
        __syncthreads();
    }
    const int dec_len = min(cums[T_ - 1], M_);
#pragma unroll
    for (int r = 0; r < M_ / T_; r++) {
        const int j = r * T_ + t;
        int lo = 0, hi = T_;
        while (lo < hi) {
            const int mid = (lo + hi) >> 1;
            if (cums[mid] <= j) lo = mid + 1; else hi = mid;
        }
        idx_out[b * M_ + j]  = min(lo, T_ - 1);
        dec_mask[b * M_ + j] = (j < dec_len) ? 1.f : 0.f;
    }
}

// ---------------------------------------------------------------------------
// mel tiled gather-GEMM (unchanged from round 2)
// ---------------------------------------------------------------------------
constexpr int JT_ = 32;
constexpr int DK_ = 128;
constexpr int LDP_ = DK_ + 4;

__global__ __launch_bounds__(256) void mel_tiled_kernel(
    const float* __restrict__ enc, const int* __restrict__ idx,
    const float* __restrict__ dec_mask, const float* __restrict__ pw,
    const float* __restrict__ pb, float* __restrict__ mel)
{
    __shared__ float As[JT_][LDP_];
    __shared__ float Ws[NMEL_][LDP_];
    __shared__ int   ids[JT_];

    const int b   = blockIdx.y;
    const int j0  = blockIdx.x * JT_;
    const int tid = threadIdx.x;

    if (tid < JT_) ids[tid] = idx[b * M_ + j0 + tid];
    __syncthreads();

    const int tx = tid & 15;
    const int ty = tid >> 4;
    const int nb = tx * 5;
    const int jb = ty * 2;

    float acc[2][5];
#pragma unroll
    for (int jj = 0; jj < 2; jj++)
#pragma unroll
        for (int k = 0; k < 5; k++) acc[jj][k] = 0.f;

    for (int d0 = 0; d0 < D_; d0 += DK_) {
        for (int i = tid; i < JT_ * (DK_ / 4); i += 256) {
            const int jj = i / (DK_ / 4);
            const int dd = (i - jj * (DK_ / 4)) * 4;
            *(float4*)(&As[jj][dd]) = *(const float4*)(
                enc + ((size_t)b * T_ + ids[jj]) * D_ + d0 + dd);
        }
        for (int i = tid; i < NMEL_ * (DK_ / 4); i += 256) {
            const int nn = i / (DK_ / 4);
            const int dd = (i - nn * (DK_ / 4)) * 4;
            *(float4*)(&Ws[nn][dd]) =
                *(const float4*)(pw + (size_t)nn * D_ + d0 + dd);
        }
        __syncthreads();

#pragma unroll 4
        for (int d = 0; d < DK_; d += 4) {
            const float4 a0 = *(const float4*)(&As[jb + 0][d]);
            const float4 a1 = *(const float4*)(&As[jb + 1][d]);
#pragma unroll
            for (int k = 0; k < 5; k++) {
                const float4 wv = *(const float4*)(&Ws[nb + k][d]);
                float s0 = acc[0][k], s1 = acc[1][k];
                s0 = fmaf(a0.x, wv.x, s0); s1 = fmaf(a1.x, wv.x, s1);
                s0 = fmaf(a0.y, wv.y, s0); s1 = fmaf(a1.y, wv.y, s1);
                s0 = fmaf(a0.z, wv.z, s0); s1 = fmaf(a1.z, wv.z, s1);
                s0 = fmaf(a0.w, wv.w, s0); s1 = fmaf(a1.w, wv.w, s1);
                acc[0][k] = s0; acc[1][k] = s1;
            }
        }
        __syncthreads();
    }

#pragma unroll
    for (int jj = 0; jj < 2; jj++) {
        const int bj = b * M_ + j0 + jb + jj;
        const float m = dec_mask[bj];
#pragma unroll
        for (int k = 0; k < 5; k++)
            mel[(size_t)bj * NMEL_ + nb + k] = m * acc[jj][k] + pb[nb + k];
    }
}

// ---------------------------------------------------------------------------
extern "C" void kernel_launch(void* const* d_in, const int* in_sizes, int n_in,
                              void* d_out, int out_size, void* d_ws, size_t ws_size,
                              hipStream_t stream)
{
    const float* enc_out   = (const float*)d_in[0];
    const float* enc_mask  = (const float*)d_in[1];
    const float* pitch_tgt = (const float*)d_in[2];
    const int*   durations = (const int*)d_in[3];

    const float* dur_c0_w = (const float*)d_in[4];
    const float* dur_c0_b = (const float*)d_in[5];
    const float* dur_n0_g = (const float*)d_in[6];
    const float* dur_n0_b = (const float*)d_in[7];
    const float* dur_c1_w = (const float*)d_in[8];
    const float* dur_c1_b = (const float*)d_in[9];
    const float* dur_n1_g = (const float*)d_in[10];
    const float* dur_n1_b = (const float*)d_in[11];
    const float* dur_fc_w = (const float*)d_in[12];
    const float* dur_fc_b = (const float*)d_in[13];

    const float* pit_c0_w = (const float*)d_in[14];
    const float* pit_c0_b = (const float*)d_in[15];
    const float* pit_n0_g = (const float*)d_in[16];
    const float* pit_n0_b = (const float*)d_in[17];
    const float* pit_c1_w = (const float*)d_in[18];
    const float* pit_c1_b = (const float*)d_in[19];
    const float* pit_n1_g = (const float*)d_in[20];
    const float* pit_n1_b = (const float*)d_in[21];
    const float* pit_fc_w = (const float*)d_in[22];
    const float* pit_fc_b = (const float*)d_in[23];

    const float* pemb_w = (const float*)d_in[24];
    const float* pemb_b = (const float*)d_in[25];
    const float* proj_w = (const float*)d_in[26];
    const float* proj_b = (const float*)d_in[27];

    // Output slices (flat, in return order), all fp32.
    float* out       = (float*)d_out;
    float* mel_out   = out;                                   // [B,M,NMEL]
    float* dec_mask  = mel_out + (size_t)B_ * M_ * NMEL_;     // [B,M,1]
    float* dur_pred  = dec_mask + (size_t)B_ * M_;            // [B,T]
    float* log_dur   = dur_pred + (size_t)B_ * T_;            // [B,T]
    float* pitch_prd = log_dur + (size_t)B_ * T_;             // [B,T]

    // Workspace layout (~13.7 MiB)
    char* wp = (char*)d_ws;
    float*          enc = (float*)wp;                 wp += (size_t)R_ * D_ * 4;   // 6.29 MB
    unsigned short* xb  = (unsigned short*)wp;        wp += (size_t)R_ * D_ * 2;   // 3.15 MB
    unsigned short* pwf = (unsigned short*)wp;        wp += (size_t)3 * F_ * D_ * 2; // 590 KB
    unsigned short* h   = (unsigned short*)wp;        wp += (size_t)R_ * F_ * 2;   // 2.10 MB
    unsigned short* hb  = (unsigned short*)wp;        wp += (size_t)R_ * F_ * 2;   // 2.10 MB
    int*            idx = (int*)wp;                                                 // 131 KB

    const dim3 blk(256);
    const int gcast = R_ * D_ / 4 / 256;       // 1536
    const int grep0 = 3 * F_ * D_ / 8 / 256;   // 144
    const int grep1 = 3 * F_ * F_ / 8 / 256;   // 96
    const int gconv = R_ / 32;                 // 128
    const int grow  = R_ / 4;                  // 1024

    // Shared bf16 input (mask folded in)
    cast_xb_kernel<<<gcast, blk, 0, stream>>>(enc_out, enc_mask, xb);

    // ---- duration predictor ----
    repack_w_kernel<D_><<<grep0, blk, 0, stream>>>(dur_c0_w, pwf);
    conv_mfma_kernel<D_><<<gconv, blk, 0, stream>>>(xb, pwf, dur_c0_b, h);
    ln_rows_kernel<<<grow, blk, 0, stream>>>(h, dur_n0_g, dur_n0_b, hb);
    repack_w_kernel<F_><<<grep1, blk, 0, stream>>>(dur_c1_w, pwf);
    conv_mfma_kernel<F_><<<gconv, blk, 0, stream>>>(hb, pwf, dur_c1_b, h);
    ln_rows_kernel<<<grow, blk, 0, stream>>>(h, dur_n1_g, dur_n1_b, hb);
    fc_mask_kernel<<<grow, blk, 0, stream>>>(hb, dur_fc_w, dur_fc_b, enc_mask, log_dur, dur_pred);

    // ---- pitch predictor ----
    repack_w_kernel<D_><<<grep0, blk, 0, stream>>>(pit_c0_w, pwf);
    conv_mfma_kernel<D_><<<gconv, blk, 0, stream>>>(xb, pwf, pit_c0_b, h);
    ln_rows_kernel<<<grow, blk, 0, stream>>>(h, pit_n0_g, pit_n0_b, hb);
    repack_w_kernel<F_><<<grep1, blk, 0, stream>>>(pit_c1_w, pwf);
    conv_mfma_kernel<F_><<<gconv, blk, 0, stream>>>(hb, pwf, pit_c1_b, h);
    ln_rows_kernel<<<grow, blk, 0, stream>>>(h, pit_n1_g, pit_n1_b, hb);
    fc_mask_kernel<<<grow, blk, 0, stream>>>(hb, pit_fc_w, pit_fc_b, enc_mask, pitch_prd, nullptr);

    // ---- decoder-side path ----
    pitch_add_kernel<<<R_ * D_ / 256, blk, 0, stream>>>(enc_out, pitch_tgt, pemb_w, pemb_b, enc);
    regulate_kernel<<<B_, blk, 0, stream>>>(durations, idx, dec_mask);
    mel_tiled_kernel<<<dim3(M_ / JT_, B_), blk, 0, stream>>>(enc, idx, dec_mask, proj_w, proj_b, mel_out);
}

// Round 4
// 180.545 us; speedup vs baseline: 5.2178x; 1.6612x over previous
//
#include <hip/hip_runtime.h>
#include <math.h>

// Problem constants (from reference)
constexpr int B_ = 16, T_ = 256, D_ = 384, M_ = 2048, F_ = 256, NMEL_ = 80;
constexpr float PACE_ = 1.0f, MAXDUR_ = 75.0f;
constexpr int R_ = B_ * T_;  // 4096 total rows

typedef __attribute__((ext_vector_type(8))) short bf16x8;
typedef __attribute__((ext_vector_type(4))) float f32x4_;

static __device__ __forceinline__ unsigned short f2bf(float x) {
    union { float f; unsigned int u; } v; v.f = x;
    const unsigned int r = v.u + 0x7fffu + ((v.u >> 16) & 1u);  // RNE
    return (unsigned short)(r >> 16);
}
static __device__ __forceinline__ float bf2f(unsigned short h) {
    union { float f; unsigned int u; } v; v.u = ((unsigned int)h) << 16;
    return v.f;
}

// ---------------------------------------------------------------------------
// Repack conv weight w[F_,CIN,3] fp32 -> bf16 16x16x32 B-fragment order:
//   p[ ((k*(F_/16) + fn)*(CIN/32) + c)*512 + lane*8 + j ]
//     = w[f = fn*16+(lane&15)][d = c*32+(lane>>4)*8+j][k]
// blockIdx.y selects (w0->p0) vs (w1->p1)  [dur vs pitch].
// ---------------------------------------------------------------------------
template <int CIN>
__global__ __launch_bounds__(256) void repack16_kernel(
    const float* __restrict__ w0, const float* __restrict__ w1,
    unsigned short* __restrict__ p0, unsigned short* __restrict__ p1)
{
    const float* w = blockIdx.y ? w1 : w0;
    unsigned short* p = blockIdx.y ? p1 : p0;
    constexpr int NC = CIN / 32;
    const int gid = blockIdx.x * 256 + threadIdx.x;   // over 3*F_*CIN/8
    const int lane = gid & 63;
    int rest = gid >> 6;
    const int c = rest % NC;  rest /= NC;
    const int fn = rest % (F_ / 16);
    const int k  = rest / (F_ / 16);
    const int f = fn * 16 + (lane & 15);
    const int d = c * 32 + (lane >> 4) * 8;
    uint4 o;
    unsigned short* op = (unsigned short*)&o;
#pragma unroll
    for (int j = 0; j < 8; j++)
        op[j] = f2bf(w[((size_t)f * CIN + d + j) * 3 + k]);
    ((uint4*)p)[gid] = o;
}

// ---------------------------------------------------------------------------
// Conv1d(K=3,SAME) + bias + ReLU via MFMA 16x16x32 bf16.
// Block: 32 t-rows x 64 f, 4 waves (each 16m x 32n, 3 tap-chains).
// Grid (R_/32, F_/64, 2): z = predictor (dur/pitch).
// FP32IN: stage loop reads fp32 (+mask) and converts; else bf16 input.
// ---------------------------------------------------------------------------
template <int CIN, bool FP32IN>
__global__ __launch_bounds__(256) void conv16_kernel(
    const void* __restrict__ in0, const void* __restrict__ in1,
    const float* __restrict__ mask,
    const unsigned short* __restrict__ pw0, const unsigned short* __restrict__ pw1,
    const float* __restrict__ bias0, const float* __restrict__ bias1,
    unsigned short* __restrict__ out0, unsigned short* __restrict__ out1)
{
    constexpr int LDX = CIN + 8;     // padded row stride (bf16), 16B aligned
    constexpr int NC  = CIN / 32;
    __shared__ unsigned short xs[34 * LDX];

    const int z = blockIdx.z;
    const void* in = z ? in1 : in0;
    const unsigned short* pw = z ? pw1 : pw0;
    const float* bias = z ? bias1 : bias0;
    unsigned short* out = z ? out1 : out0;

    const int r0  = blockIdx.x * 32;   // 32-row tiles never cross a batch
    const int bb  = r0 >> 8;
    const int tl  = r0 & 255;
    const int tid = threadIdx.x;

    // Stage x rows tl-1 .. tl+32 (34 rows), zero outside batch.
    if (FP32IN) {
        const float* x = (const float*)in;
        for (int i = tid; i < 34 * (CIN / 8); i += 256) {
            const int row = i / (CIN / 8);
            const int dd  = (i - row * (CIN / 8)) * 8;
            const int t   = tl - 1 + row;
            ushort4 o0 = {0, 0, 0, 0}, o1 = {0, 0, 0, 0};
            if (t >= 0 && t < 256) {
                const float m = mask[bb * 256 + t];
                const float* xr = x + (size_t)(bb * 256 + t) * CIN + dd;
                const float4 v0 = *(const float4*)xr;
                const float4 v1 = *(const float4*)(xr + 4);
                o0.x = f2bf(v0.x * m); o0.y = f2bf(v0.y * m);
                o0.z = f2bf(v0.z * m); o0.w = f2bf(v0.w * m);
                o1.x = f2bf(v1.x * m); o1.y = f2bf(v1.y * m);
                o1.z = f2bf(v1.z * m); o1.w = f2bf(v1.w * m);
            }
            *(ushort4*)(&xs[row * LDX + dd])     = o0;
            *(ushort4*)(&xs[row * LDX + dd + 4]) = o1;
        }
    } else {
        const unsigned short* x = (const unsigned short*)in;
        for (int i = tid; i < 34 * (CIN / 8); i += 256) {
            const int row = i / (CIN / 8);
            const int dd  = (i - row * (CIN / 8)) * 8;
            const int t   = tl - 1 + row;
            uint4 v = make_uint4(0, 0, 0, 0);
            if (t >= 0 && t < 256)
                v = *(const uint4*)(x + (size_t)(bb * 256 + t) * CIN + dd);
            *(uint4*)(&xs[row * LDX + dd]) = v;
        }
    }
    __syncthreads();

    const int w = tid >> 6, l = tid & 63;
    const int q = l >> 4, lm = l & 15;
    const int m0  = (w & 1) * 16;
    const int fnB = blockIdx.y * 4 + (w >> 1) * 2;   // global f-tile (of 16)

    f32x4_ acc[2][3];
#pragma unroll
    for (int nf = 0; nf < 2; nf++)
#pragma unroll
        for (int k = 0; k < 3; k++)
#pragma unroll
            for (int i = 0; i < 4; i++) acc[nf][k][i] = 0.f;

    for (int c = 0; c < NC; c++) {
        bf16x8 a[3];
#pragma unroll
        for (int tap = 0; tap < 3; tap++)
            a[tap] = *(const bf16x8*)(&xs[(m0 + lm + tap) * LDX + c * 32 + q * 8]);
#pragma unroll
        for (int tap = 0; tap < 3; tap++) {
#pragma unroll
            for (int nf = 0; nf < 2; nf++) {
                const bf16x8 b = *(const bf16x8*)(
                    pw + ((((size_t)tap * (F_ / 16) + fnB + nf) * NC + c) << 9) + l * 8);
                acc[nf][tap] = __builtin_amdgcn_mfma_f32_16x16x32_bf16(
                    a[tap], b, acc[nf][tap], 0, 0, 0);
            }
        }
    }

    // C/D 16x16 layout: col=lane&15 (n), row=(lane>>4)*4+reg (m)  [m89/m91]
#pragma unroll
    for (int nf = 0; nf < 2; nf++) {
        const int f = (fnB + nf) * 16 + lm;
        const float bs = bias[f];
#pragma unroll
        for (int r = 0; r < 4; r++) {
            const int m = m0 + q * 4 + r;
            const float v = acc[nf][0][r] + acc[nf][1][r] + acc[nf][2][r] + bs;
            out[(size_t)(r0 + m) * F_ + f] = f2bf(fmaxf(v, 0.f));
        }
    }
}

// ---------------------------------------------------------------------------
// LayerNorm over 256 channels, one wave per row, dur+pitch via blockIdx.y.
// ---------------------------------------------------------------------------
__global__ __launch_bounds__(256) void ln2_kernel(
    const unsigned short* __restrict__ in0, const unsigned short* __restrict__ in1,
    const float* __restrict__ g0, const float* __restrict__ b0,
    const float* __restrict__ g1, const float* __restrict__ b1,
    unsigned short* __restrict__ o0, unsigned short* __restrict__ o1)
{
    const unsigned short* h = blockIdx.y ? in1 : in0;
    const float* g  = blockIdx.y ? g1 : g0;
    const float* be = blockIdx.y ? b1 : b0;
    unsigned short* o = blockIdx.y ? o1 : o0;

    const int row  = blockIdx.x * 4 + (threadIdx.x >> 6);
    const int lane = threadIdx.x & 63;
    const ushort4 hv = ((const ushort4*)(h + (size_t)row * F_))[lane];
    const float v0 = bf2f(hv.x), v1 = bf2f(hv.y), v2 = bf2f(hv.z), v3 = bf2f(hv.w);
    float sm = v0 + v1 + v2 + v3;
    float sq = v0 * v0 + v1 * v1 + v2 * v2 + v3 * v3;
#pragma unroll
    for (int off = 32; off >= 1; off >>= 1) {
        sm += __shfl_xor(sm, off);
        sq += __shfl_xor(sq, off);
    }
    const float mu = sm * (1.f / F_);
    const float rs = rsqrtf(sq * (1.f / F_) - mu * mu + 1e-5f);
    const float4 gv = ((const float4*)g)[lane];
    const float4 bv = ((const float4*)be)[lane];
    ushort4 ov;
    ov.x = f2bf((v0 - mu) * rs * gv.x + bv.x);
    ov.y = f2bf((v1 - mu) * rs * gv.y + bv.y);
    ov.z = f2bf((v2 - mu) * rs * gv.z + bv.z);
    ov.w = f2bf((v3 - mu) * rs * gv.w + bv.w);
    ((ushort4*)(o + (size_t)row * F_))[lane] = ov;
}

// ---------------------------------------------------------------------------
// FC heads (dur & pitch via blockIdx.y): pred = (dot(h,fcw)+fcb)*mask
// ---------------------------------------------------------------------------
__global__ __launch_bounds__(256) void fc2_kernel(
    const unsigned short* __restrict__ h0, const unsigned short* __restrict__ h1,
    const float* __restrict__ w0, const float* __restrict__ w1,
    const float* __restrict__ cb0, const float* __restrict__ cb1,
    const float* __restrict__ mask,
    float* __restrict__ pred0, float* __restrict__ pred1,
    float* __restrict__ durpred)
{
    const unsigned short* h = blockIdx.y ? h1 : h0;
    const float* fcw = blockIdx.y ? w1 : w0;
    const float* fcb = blockIdx.y ? cb1 : cb0;
    float* pred = blockIdx.y ? pred1 : pred0;
    float* dp   = blockIdx.y ? nullptr : durpred;

    const int row  = blockIdx.x * 4 + (threadIdx.x >> 6);
    const int lane = threadIdx.x & 63;
    const ushort4 hv = ((const ushort4*)(h + (size_t)row * F_))[lane];
    const float4 wv = ((const float4*)fcw)[lane];
    float s = bf2f(hv.x) * wv.x + bf2f(hv.y) * wv.y +
              bf2f(hv.z) * wv.z + bf2f(hv.w) * wv.w;
#pragma unroll
    for (int off = 32; off >= 1; off >>= 1) s += __shfl_xor(s, off);
    if (lane == 0) {
        const float p = (s + fcb[0]) * mask[row];
        pred[row] = p;
        if (dp) dp[row] = fminf(fmaxf(expf(p) - 1.f, 0.f), MAXDUR_);
    }
}

// ---------------------------------------------------------------------------
// enc_b[b,t,d] = bf16( enc_out[b,t,d] + Conv1d(1->D,K=3)(pitch_tgt)[b,d,t] )
// ---------------------------------------------------------------------------
__global__ __launch_bounds__(256) void pitch_add_kernel(
    const float* __restrict__ enc_out, const float* __restrict__ pt,
    const float* __restrict__ we, const float* __restrict__ be,
    unsigned short* __restrict__ encb)
{
    const int gid = blockIdx.x * 256 + threadIdx.x;  // over B*T*D exactly
    const int d  = gid % D_;
    const int bt = gid / D_;
    const int t = bt % T_, b = bt / T_;
    float s = be[d];
#pragma unroll
    for (int k = 0; k < 3; k++) {
        const int t2 = t - 1 + k;
        if (t2 >= 0 && t2 < T_) s = fmaf(we[d * 3 + k], pt[b * T_ + t2], s);
    }
    encb[gid] = f2bf(enc_out[gid] + s);
}

// ---------------------------------------------------------------------------
// regulate_len prep: cumsum + searchsorted-right -> idx, dec_mask
// ---------------------------------------------------------------------------
__global__ __launch_bounds__(256) void regulate_kernel(
    const int* __restrict__ dur, int* __restrict__ idx_out,
    float* __restrict__ dec_mask)
{
    __shared__ int cums[T_];
    const int b = blockIdx.x, t = threadIdx.x;
    cums[t] = (int)rintf((float)dur[b * T_ + t] / PACE_);
    __syncthreads();
    for (int off = 1; off < T_; off <<= 1) {
        int v = cums[t];
        if (t >= off) v += cums[t - off];
        __syncthreads();
        cums[t] = v;
        __syncthreads();
    }
    const int dec_len = min(cums[T_ - 1], M_);
#pragma unroll
    for (int r = 0; r < M_ / T_; r++) {
        const int j = r * T_ + t;
        int lo = 0, hi = T_;
        while (lo < hi) {
            const int mid = (lo + hi) >> 1;
            if (cums[mid] <= j) lo = mid + 1; else hi = mid;
        }
        idx_out[b * M_ + j]  = min(lo, T_ - 1);
        dec_mask[b * M_ + j] = (j < dec_len) ? 1.f : 0.f;
    }
}

// ---------------------------------------------------------------------------
// Repack proj_w[NMEL_, D_] -> bf16 B-frag order:
//   p[(c*5 + nt)*512 + lane*8 + j] = pw[n=nt*16+(lane&15)][k=c*32+(lane>>4)*8+j]
// ---------------------------------------------------------------------------
__global__ __launch_bounds__(256) void repack_proj_kernel(
    const float* __restrict__ pw, unsigned short* __restrict__ p)
{
    const int gid = blockIdx.x * 256 + threadIdx.x;  // over 5*12*64 = 3840
    const int lane = gid & 63;
    const int rest = gid >> 6;
    const int nt = rest % 5;
    const int c  = rest / 5;
    const int n = nt * 16 + (lane & 15);
    const int k = c * 32 + (lane >> 4) * 8;
    uint4 o;
    unsigned short* op = (unsigned short*)&o;
#pragma unroll
    for (int j = 0; j < 8; j++)
        op[j] = f2bf(pw[(size_t)n * D_ + k + j]);
    ((uint4*)p)[gid] = o;
}

// ---------------------------------------------------------------------------
// mel gather-GEMM via MFMA 16x16x32:
//   mel[b,j,n] = dec_mask[b,j]*dot(enc_b[b,idx[b,j],:], proj_w[n,:]) + pb[n]
// Block: 64 j-rows (4 waves x 16), N=80 (5 n-frags). A gathered from global
// (idx monotone -> overlapping lines, L1/L2 hits); B from packed global.
// ---------------------------------------------------------------------------
__global__ __launch_bounds__(256) void mel_mfma_kernel(
    const unsigned short* __restrict__ encb, const int* __restrict__ idx,
    const float* __restrict__ dmask, const unsigned short* __restrict__ pwb,
    const float* __restrict__ pb, float* __restrict__ mel)
{
    __shared__ int ids[64];
    const int b  = blockIdx.y;
    const int j0 = blockIdx.x * 64;
    const int tid = threadIdx.x;
    if (tid < 64) ids[tid] = idx[b * M_ + j0 + tid];
    __syncthreads();

    const int w = tid >> 6, l = tid & 63;
    const int q = l >> 4, lm = l & 15;
    const int row = ids[w * 16 + lm];
    const unsigned short* ap = encb + ((size_t)(b * 256 + row)) * D_ + q * 8;

    f32x4_ acc[5];
#pragma unroll
    for (int nt = 0; nt < 5; nt++)
#pragma unroll
        for (int i = 0; i < 4; i++) acc[nt][i] = 0.f;

    for (int c = 0; c < D_ / 32; c++) {
        const bf16x8 a = *(const bf16x8*)(ap + c * 32);
#pragma unroll
        for (int nt = 0; nt < 5; nt++) {
            const bf16x8 bv = *(const bf16x8*)(pwb + (((size_t)c * 5 + nt) << 9) + l * 8);
            acc[nt] = __builtin_amdgcn_mfma_f32_16x16x32_bf16(a, bv, acc[nt], 0, 0, 0);
        }
    }

    float msk[4];
#pragma unroll
    for (int r = 0; r < 4; r++)
        msk[r] = dmask[b * M_ + j0 + w * 16 + q * 4 + r];
#pragma unroll
    for (int nt = 0; nt < 5; nt++) {
        const int n = nt * 16 + lm;
        const float bb = pb[n];
#pragma unroll
        for (int r = 0; r < 4; r++) {
            const int j = j0 + w * 16 + q * 4 + r;
            mel[((size_t)b * M_ + j) * NMEL_ + n] = msk[r] * acc[nt][r] + bb;
        }
    }
}

// ---------------------------------------------------------------------------
extern "C" void kernel_launch(void* const* d_in, const int* in_sizes, int n_in,
                              void* d_out, int out_size, void* d_ws, size_t ws_size,
                              hipStream_t stream)
{
    const float* enc_out   = (const float*)d_in[0];
    const float* enc_mask  = (const float*)d_in[1];
    const float* pitch_tgt = (const float*)d_in[2];
    const int*   durations = (const int*)d_in[3];

    const float* dur_c0_w = (const float*)d_in[4];
    const float* dur_c0_b = (const float*)d_in[5];
    const float* dur_n0_g = (const float*)d_in[6];
    const float* dur_n0_b = (const float*)d_in[7];
    const float* dur_c1_w = (const float*)d_in[8];
    const float* dur_c1_b = (const float*)d_in[9];
    const float* dur_n1_g = (const float*)d_in[10];
    const float* dur_n1_b = (const float*)d_in[11];
    const float* dur_fc_w = (const float*)d_in[12];
    const float* dur_fc_b = (const float*)d_in[13];

    const float* pit_c0_w = (const float*)d_in[14];
    const float* pit_c0_b = (const float*)d_in[15];
    const float* pit_n0_g = (const float*)d_in[16];
    const float* pit_n0_b = (const float*)d_in[17];
    const float* pit_c1_w = (const float*)d_in[18];
    const float* pit_c1_b = (const float*)d_in[19];
    const float* pit_n1_g = (const float*)d_in[20];
    const float* pit_n1_b = (const float*)d_in[21];
    const float* pit_fc_w = (const float*)d_in[22];
    const float* pit_fc_b = (const float*)d_in[23];

    const float* pemb_w = (const float*)d_in[24];
    const float* pemb_b = (const float*)d_in[25];
    const float* proj_w = (const float*)d_in[26];
    const float* proj_b = (const float*)d_in[27];

    // Output slices (flat, in return order), all fp32.
    float* out       = (float*)d_out;
    float* mel_out   = out;                                   // [B,M,NMEL]
    float* dec_mask  = mel_out + (size_t)B_ * M_ * NMEL_;     // [B,M,1]
    float* dur_pred  = dec_mask + (size_t)B_ * M_;            // [B,T]
    float* log_dur   = dur_pred + (size_t)B_ * T_;            // [B,T]
    float* pitch_prd = log_dur + (size_t)B_ * T_;             // [B,T]

    // Workspace layout (~12.9 MiB)
    char* wp = (char*)d_ws;
    unsigned short* h_d  = (unsigned short*)wp; wp += (size_t)R_ * F_ * 2;      // 2.10 MB
    unsigned short* h_p  = (unsigned short*)wp; wp += (size_t)R_ * F_ * 2;      // 2.10 MB
    unsigned short* hb_d = (unsigned short*)wp; wp += (size_t)R_ * F_ * 2;      // 2.10 MB
    unsigned short* hb_p = (unsigned short*)wp; wp += (size_t)R_ * F_ * 2;      // 2.10 MB
    unsigned short* pwA  = (unsigned short*)wp; wp += (size_t)3 * F_ * D_ * 2;  // 590 KB
    unsigned short* pwB  = (unsigned short*)wp; wp += (size_t)3 * F_ * D_ * 2;  // 590 KB
    unsigned short* encb = (unsigned short*)wp; wp += (size_t)R_ * D_ * 2;      // 3.15 MB
    unsigned short* pwb  = (unsigned short*)wp; wp += (size_t)5 * 12 * 512 * 2; // 61 KB
    int*            idx  = (int*)wp;                                            // 131 KB

    const dim3 blk(256);
    const dim3 gconv(R_ / 32, F_ / 64, 2);   // (128, 4, 2)
    const dim3 grow(R_ / 4, 2);              // (1024, 2)

    // conv0 weights (dur + pitch) -> fragment order
    repack16_kernel<D_><<<dim3(3 * F_ * D_ / 8 / 256, 2), blk, 0, stream>>>(
        dur_c0_w, pit_c0_w, pwA, pwB);
    // conv0 both predictors (reads enc_out fp32 * mask, converts in stage loop)
    conv16_kernel<D_, true><<<gconv, blk, 0, stream>>>(
        enc_out, enc_out, enc_mask, pwA, pwB, dur_c0_b, pit_c0_b, h_d, h_p);
    ln2_kernel<<<grow, blk, 0, stream>>>(
        h_d, h_p, dur_n0_g, dur_n0_b, pit_n0_g, pit_n0_b, hb_d, hb_p);
    // conv1 weights (reuse pwA/pwB after conv0 completed — stream-ordered)
    repack16_kernel<F_><<<dim3(3 * F_ * F_ / 8 / 256, 2), blk, 0, stream>>>(
        dur_c1_w, pit_c1_w, pwA, pwB);
    conv16_kernel<F_, false><<<gconv, blk, 0, stream>>>(
        hb_d, hb_p, nullptr, pwA, pwB, dur_c1_b, pit_c1_b, h_d, h_p);
    ln2_kernel<<<grow, blk, 0, stream>>>(
        h_d, h_p, dur_n1_g, dur_n1_b, pit_n1_g, pit_n1_b, hb_d, hb_p);
    fc2_kernel<<<grow, blk, 0, stream>>>(
        hb_d, hb_p, dur_fc_w, pit_fc_w, dur_fc_b, pit_fc_b, enc_mask,
        log_dur, pitch_prd, dur_pred);

    // decoder-side path
    pitch_add_kernel<<<R_ * D_ / 256, blk, 0, stream>>>(
        enc_out, pitch_tgt, pemb_w, pemb_b, encb);
    regulate_kernel<<<B_, blk, 0, stream>>>(durations, idx, dec_mask);
    repack_proj_kernel<<<15, blk, 0, stream>>>(proj_w, pwb);
    mel_mfma_kernel<<<dim3(M_ / 64, B_), blk, 0, stream>>>(
        encb, idx, dec_mask, pwb, proj_b, mel_out);
}